// Round 8
// baseline (277.899 us; speedup 1.0000x reference)
//
#include <hip/hip_runtime.h>
#include <math.h>

#define NG   512
#define NPER 256
#define DD   128
#define EPER 4096
#define KK   128
#define NT   1024
#define NW   16     // waves per block

#define SFX_SCALE 4194304.0f             // 2^22
#define SFX_INV   2.384185791015625e-07f // 2^-22

// LDS-only barrier (R6): lgkmcnt drain + s_barrier, no vmcnt drain.
#define BAR() asm volatile("s_waitcnt lgkmcnt(0)\ns_barrier" ::: "memory")

// Probe sink (prevents DCE; not part of checked output).
__device__ float g_sink[(size_t)NG * NT];

// ---------------------------------------------------------------------------
// REAL kernel: R6 fused (current best, 119.0 us harness). Unchanged.
// ---------------------------------------------------------------------------
__global__ __launch_bounds__(NT, 8) void sag_fused(
    const float* __restrict__ x,
    const int*   __restrict__ esrc,
    const int*   __restrict__ edst,
    const float* __restrict__ gcn_w,
    const float* __restrict__ gcn_b,
    const float* __restrict__ lin_w,
    const float* __restrict__ lin_b,
    float* __restrict__ out)
{
  const int g    = blockIdx.x;
  const int tid  = threadIdx.x;
  const int lane = tid & 63;
  const int wave = tid >> 6;
  const int j    = lane & 15;
  const int sub  = lane >> 4;
  const int slot = wave * 4 + sub;

  __shared__ int    sDeg[NPER];
  __shared__ int    sRank[NPER];
  __shared__ int    sXWi[NPER];
  __shared__ __align__(16) int   sFx[NPER];
  __shared__ float  sXW[NPER];
  __shared__ float  sDinv[NPER];
  __shared__ __align__(16) float sScore[NPER];
  __shared__ float2 sGF[NPER];
  __shared__ float  sPoolS[NW][DD];
  __shared__ float  sPoolM[NW][DD];
  __shared__ float2 sR2[DD];
  float* sR = (float*)sR2;

  const int4* es4 = (const int4*)(esrc + (size_t)g * EPER);
  const int4* ed4 = (const int4*)(edst + (size_t)g * EPER);
  int4 da = ed4[tid];
  int4 sa = es4[tid];

  float4 wa = ((const float4*)gcn_w)[j];
  float4 wb = ((const float4*)gcn_w)[16 + j];

  const float4* xg4 = (const float4*)(x + (size_t)g * NPER * DD);
  const int colbase = slot * 32 + j;
  float4 q0[4], q1[4];
  #pragma unroll
  for (int r = 0; r < 4; ++r) {
    q0[r] = xg4[r * 2048 + colbase];
    q1[r] = xg4[r * 2048 + colbase + 16];
  }

  if (tid < NPER) { sDeg[tid] = 1; sRank[tid] = 0; }
  BAR();                                                // B1

  atomicAdd(&sDeg[da.x & 255], 1);
  atomicAdd(&sDeg[da.y & 255], 1);
  atomicAdd(&sDeg[da.z & 255], 1);
  atomicAdd(&sDeg[da.w & 255], 1);

  #pragma unroll
  for (int r = 0; r < 4; ++r) {
    float acc = q0[r].x*wa.x + q0[r].y*wa.y + q0[r].z*wa.z + q0[r].w*wa.w
              + q1[r].x*wb.x + q1[r].y*wb.y + q1[r].z*wb.z + q1[r].w*wb.w;
    acc += __shfl_xor(acc, 1);
    acc += __shfl_xor(acc, 2);
    acc += __shfl_xor(acc, 4);
    acc += __shfl_xor(acc, 8);
    if (j == 0) sXW[r * 64 + slot] = acc;
  }
  BAR();                                                // B2

  if (tid < NPER) {
    float dv = 1.0f / sqrtf((float)sDeg[tid]);
    int   xi = __float2int_rn(sXW[tid] * dv * SFX_SCALE);
    sDinv[tid] = dv;
    sXWi[tid]  = xi;
    sFx[tid]   = xi;
  }
  BAR();                                                // B3

  {
    int v0 = sXWi[sa.x & 255];
    int v1 = sXWi[sa.y & 255];
    int v2 = sXWi[sa.z & 255];
    int v3 = sXWi[sa.w & 255];
    atomicAdd(&sFx[da.x & 255], v0);
    atomicAdd(&sFx[da.y & 255], v1);
    atomicAdd(&sFx[da.z & 255], v2);
    atomicAdd(&sFx[da.w & 255], v3);
  }
  BAR();                                                // B4

  if (tid < NPER) sScore[tid] = sDinv[tid] * ((float)sFx[tid] * SFX_INV);
  BAR();                                                // B4b

  {
    const float4* sScore4 = (const float4*)sScore;
    int node = tid & 255;
    int seg  = tid >> 8;
    float s_i = sScore[node];
    int base = seg * 16;
    int part = 0;
    #pragma unroll 8
    for (int t = 0; t < 16; ++t) {
      float4 v = sScore4[base + t];
      int jj = (base + t) * 4;
      part += (v.x > s_i) || (v.x == s_i && (jj + 0) < node);
      part += (v.y > s_i) || (v.y == s_i && (jj + 1) < node);
      part += (v.z > s_i) || (v.z == s_i && (jj + 2) < node);
      part += (v.w > s_i) || (v.w == s_i && (jj + 3) < node);
    }
    atomicAdd(&sRank[node], part);
  }
  BAR();                                                // B5

  if (tid < NPER) {
    bool kp = sRank[tid] < KK;
    float gate = tanhf(sScore[tid] + gcn_b[0]);
    sGF[tid] = make_float2(kp ? gate : 0.0f, kp ? 0.0f : INFINITY);
  }
  BAR();                                                // B6

  float su0=0,su1=0,su2=0,su3=0,su4=0,su5=0,su6=0,su7=0;
  float mx0=-INFINITY,mx1=-INFINITY,mx2=-INFINITY,mx3=-INFINITY;
  float mx4=-INFINITY,mx5=-INFINITY,mx6=-INFINITY,mx7=-INFINITY;
  #pragma unroll
  for (int r = 0; r < 4; ++r) {
    float2 gf = sGF[r * 64 + slot];
    float g1 = gf.x, fb = gf.y;
    float a;
    a = q0[r].x * g1; su0 += a; mx0 = fmaxf(mx0, a - fb);
    a = q0[r].y * g1; su1 += a; mx1 = fmaxf(mx1, a - fb);
    a = q0[r].z * g1; su2 += a; mx2 = fmaxf(mx2, a - fb);
    a = q0[r].w * g1; su3 += a; mx3 = fmaxf(mx3, a - fb);
    a = q1[r].x * g1; su4 += a; mx4 = fmaxf(mx4, a - fb);
    a = q1[r].y * g1; su5 += a; mx5 = fmaxf(mx5, a - fb);
    a = q1[r].z * g1; su6 += a; mx6 = fmaxf(mx6, a - fb);
    a = q1[r].w * g1; su7 += a; mx7 = fmaxf(mx7, a - fb);
  }
  #define RED_S(v) v += __shfl_xor(v,16); v += __shfl_xor(v,32);
  #define RED_M(v) v = fmaxf(v,__shfl_xor(v,16)); v = fmaxf(v,__shfl_xor(v,32));
  RED_S(su0) RED_S(su1) RED_S(su2) RED_S(su3)
  RED_S(su4) RED_S(su5) RED_S(su6) RED_S(su7)
  RED_M(mx0) RED_M(mx1) RED_M(mx2) RED_M(mx3)
  RED_M(mx4) RED_M(mx5) RED_M(mx6) RED_M(mx7)
  if (sub == 0) {
    ((float4*)&sPoolS[wave][4 * j])[0]      = make_float4(su0, su1, su2, su3);
    ((float4*)&sPoolS[wave][64 + 4 * j])[0] = make_float4(su4, su5, su6, su7);
    ((float4*)&sPoolM[wave][4 * j])[0]      = make_float4(mx0, mx1, mx2, mx3);
    ((float4*)&sPoolM[wave][64 + 4 * j])[0] = make_float4(mx4, mx5, mx6, mx7);
  }
  BAR();                                                // B7

  if (tid < DD) {
    float s = 0.f;
    #pragma unroll
    for (int w = 0; w < NW; ++w) s += sPoolS[w][tid];
    sR[tid] = s * (1.0f / KK);
  } else if (tid < 2 * DD) {
    int d = tid - DD;
    float m = -INFINITY;
    #pragma unroll
    for (int w = 0; w < NW; ++w) m = fmaxf(m, sPoolM[w][d]);
    sR[tid] = m;
  }
  BAR();                                                // B8

  const float2* lw2 = (const float2*)lin_w;
  float a0 = 0.f, a1 = 0.f;
  #pragma unroll
  for (int t = 0; t < 8; ++t) {
    int k2 = wave * 8 + t;
    float2 rv = sR2[k2];
    float2 p0 = lw2[(2 * k2) * 64 + lane];
    float2 p1 = lw2[(2 * k2 + 1) * 64 + lane];
    a0 += rv.x * p0.x + rv.y * p1.x;
    a1 += rv.x * p0.y + rv.y * p1.y;
  }
  float2* sP2 = (float2*)sPoolS;
  sP2[wave * 64 + lane] = make_float2(a0, a1);
  BAR();                                                // B9
  if (wave == 0) {
    float2 a = sP2[lane];
    #pragma unroll
    for (int w = 1; w < NW; ++w) { float2 p = sP2[w * 64 + lane]; a.x += p.x; a.y += p.y; }
    float2 bb = ((const float2*)lin_b)[lane];
    a.x += bb.x; a.y += bb.y;
    ((float2*)out)[(size_t)g * 64 + lane] = a;
  }
}

// ---------------------------------------------------------------------------
// PROBE 1: the front-load burst only, x16. Measures delivery rate of our
// exact access pattern (dur/16), HBM vs cache mix (FETCH_SIZE), VALU share.
// Laundered zero offset defeats CSE across iterations.
// ---------------------------------------------------------------------------
__global__ __launch_bounds__(NT, 8) void probe_load(
    const float* __restrict__ x,
    const int*   __restrict__ esrc,
    const int*   __restrict__ edst,
    const float* __restrict__ gcn_w)
{
  const int g    = blockIdx.x;
  const int tid  = threadIdx.x;
  const int lane = tid & 63;
  const int wave = tid >> 6;
  const int j    = lane & 15;
  const int sub  = lane >> 4;
  const int slot = wave * 4 + sub;
  const int colbase = slot * 32 + j;

  int zero;
  asm volatile("s_mov_b32 %0, 0" : "=s"(zero));

  float facc = 0.f;
  int   iacc = 0;
  for (int t = 0; t < 16; ++t) {
    const int off = zero * t;                 // opaque 0
    const int4* es4 = (const int4*)(esrc + (size_t)g * EPER + off);
    const int4* ed4 = (const int4*)(edst + (size_t)g * EPER + off);
    int4 sa = es4[tid];
    int4 da = ed4[tid];
    const float4* wv = (const float4*)(gcn_w + off);
    float4 wa = wv[j], wb = wv[16 + j];
    const float4* xg4 = (const float4*)(x + (size_t)g * NPER * DD + off);
    float4 q0[4], q1[4];
    #pragma unroll
    for (int r = 0; r < 4; ++r) {
      q0[r] = xg4[r * 2048 + colbase];
      q1[r] = xg4[r * 2048 + colbase + 16];
    }
    iacc += sa.x + sa.y + sa.z + sa.w + da.x + da.y + da.z + da.w;
    facc += wa.x + wa.y + wa.z + wa.w + wb.x + wb.y + wb.z + wb.w;
    #pragma unroll
    for (int r = 0; r < 4; ++r) {
      facc += q0[r].x + q0[r].y + q0[r].z + q0[r].w
            + q1[r].x + q1[r].y + q1[r].z + q1[r].w;
    }
  }
  g_sink[(size_t)g * NT + tid] = facc + (float)iacc;
}

// ---------------------------------------------------------------------------
// PROBE 2: the full score path (load -> deg -> dot -> scatter -> rank ->
// gate), x3. dur/3 = score-path time; counters attribute it to a pipe.
// ---------------------------------------------------------------------------
__global__ __launch_bounds__(NT, 8) void probe_score(
    const float* __restrict__ x,
    const int*   __restrict__ esrc,
    const int*   __restrict__ edst,
    const float* __restrict__ gcn_w,
    const float* __restrict__ gcn_b)
{
  const int g    = blockIdx.x;
  const int tid  = threadIdx.x;
  const int lane = tid & 63;
  const int wave = tid >> 6;
  const int j    = lane & 15;
  const int sub  = lane >> 4;
  const int slot = wave * 4 + sub;
  const int colbase = slot * 32 + j;

  __shared__ int    sDeg[NPER];
  __shared__ int    sRank[NPER];
  __shared__ int    sXWi[NPER];
  __shared__ __align__(16) int   sFx[NPER];
  __shared__ float  sXW[NPER];
  __shared__ float  sDinv[NPER];
  __shared__ __align__(16) float sScore[NPER];

  int zero;
  asm volatile("s_mov_b32 %0, 0" : "=s"(zero));

  float acc = 0.f;
  for (int t = 0; t < 3; ++t) {
    const int off = zero * t;                 // opaque 0
    const int4* es4 = (const int4*)(esrc + (size_t)g * EPER + off);
    const int4* ed4 = (const int4*)(edst + (size_t)g * EPER + off);
    int4 da = ed4[tid];
    int4 sa = es4[tid];
    const float4* wv = (const float4*)(gcn_w + off);
    float4 wa = wv[j], wb = wv[16 + j];
    const float4* xg4 = (const float4*)(x + (size_t)g * NPER * DD + off);
    float4 q0[4], q1[4];
    #pragma unroll
    for (int r = 0; r < 4; ++r) {
      q0[r] = xg4[r * 2048 + colbase];
      q1[r] = xg4[r * 2048 + colbase + 16];
    }

    if (tid < NPER) { sDeg[tid] = 1; sRank[tid] = 0; }
    BAR();                                            // B1

    atomicAdd(&sDeg[da.x & 255], 1);
    atomicAdd(&sDeg[da.y & 255], 1);
    atomicAdd(&sDeg[da.z & 255], 1);
    atomicAdd(&sDeg[da.w & 255], 1);

    #pragma unroll
    for (int r = 0; r < 4; ++r) {
      float a = q0[r].x*wa.x + q0[r].y*wa.y + q0[r].z*wa.z + q0[r].w*wa.w
              + q1[r].x*wb.x + q1[r].y*wb.y + q1[r].z*wb.z + q1[r].w*wb.w;
      a += __shfl_xor(a, 1);
      a += __shfl_xor(a, 2);
      a += __shfl_xor(a, 4);
      a += __shfl_xor(a, 8);
      if (j == 0) sXW[r * 64 + slot] = a;
    }
    BAR();                                            // B2

    if (tid < NPER) {
      float dv = 1.0f / sqrtf((float)sDeg[tid]);
      int   xi = __float2int_rn(sXW[tid] * dv * SFX_SCALE);
      sDinv[tid] = dv;
      sXWi[tid]  = xi;
      sFx[tid]   = xi;
    }
    BAR();                                            // B3

    {
      int v0 = sXWi[sa.x & 255];
      int v1 = sXWi[sa.y & 255];
      int v2 = sXWi[sa.z & 255];
      int v3 = sXWi[sa.w & 255];
      atomicAdd(&sFx[da.x & 255], v0);
      atomicAdd(&sFx[da.y & 255], v1);
      atomicAdd(&sFx[da.z & 255], v2);
      atomicAdd(&sFx[da.w & 255], v3);
    }
    BAR();                                            // B4

    if (tid < NPER) sScore[tid] = sDinv[tid] * ((float)sFx[tid] * SFX_INV);
    BAR();                                            // B4b

    {
      const float4* sScore4 = (const float4*)sScore;
      int node = tid & 255;
      int seg  = tid >> 8;
      float s_i = sScore[node];
      int base = seg * 16;
      int part = 0;
      #pragma unroll 8
      for (int u = 0; u < 16; ++u) {
        float4 v = sScore4[base + u];
        int jj = (base + u) * 4;
        part += (v.x > s_i) || (v.x == s_i && (jj + 0) < node);
        part += (v.y > s_i) || (v.y == s_i && (jj + 1) < node);
        part += (v.z > s_i) || (v.z == s_i && (jj + 2) < node);
        part += (v.w > s_i) || (v.w == s_i && (jj + 3) < node);
      }
      atomicAdd(&sRank[node], part);
    }
    BAR();                                            // B5

    if (tid < NPER) {
      bool kp = sRank[tid] < KK;
      float gate = tanhf(sScore[tid] + gcn_b[0]);
      acc += kp ? gate : 0.0f;
    }
    BAR();                                            // B6 (loop boundary)
  }
  g_sink[(size_t)g * NT + tid] = acc;
}

extern "C" void kernel_launch(void* const* d_in, const int* in_sizes, int n_in,
                              void* d_out, int out_size, void* d_ws, size_t ws_size,
                              hipStream_t stream) {
  const float* x  = (const float*)d_in[0];
  // d_in[1] = graph_indicator (unused)
  const int*   ei = (const int*)d_in[2];
  const float* gw = (const float*)d_in[3];
  const float* gb = (const float*)d_in[4];
  const float* lw = (const float*)d_in[5];
  const float* lb = (const float*)d_in[6];
  float* out = (float*)d_out;
  const int E = in_sizes[2] / 2;

  // probe_load FIRST: sees the same post-poison cache state the real kernel
  // has been measured in for 7 rounds (iter 1 = that state; iters 2-16 = L3).
  probe_load <<<NG, NT, 0, stream>>>(x, ei, ei + E, gw);
  sag_fused  <<<NG, NT, 0, stream>>>(x, ei, ei + E, gw, gb, lw, lb, out);
  probe_score<<<NG, NT, 0, stream>>>(x, ei, ei + E, gw, gb);
}

// Round 9
// 130.876 us; speedup vs baseline: 2.1234x; 2.1234x over previous
//
#include <hip/hip_runtime.h>
#include <math.h>

#define NG   512
#define NPER 256
#define DD   128
#define EPER 4096
#define KK   128
#define NT   1024

#define SFX_SCALE 4194304.0f             // 2^22
#define SFX_INV   2.384185791015625e-07f // 2^-22

// LDS-only barrier (lgkm drain + s_barrier, no vmcnt drain): global loads
// issued before it stay in flight across phases; compiler inserts counted
// vmcnt waits at first use.
#define BAR() asm volatile("s_waitcnt lgkmcnt(0)\ns_barrier" ::: "memory")

// Two graphs per block, fused per-phase. Probe evidence (R8): warm score
// chain = 18.7us with only ~5us of pipe time -> dependent-LDS-latency
// stalls dominate. Interleaving two independent graphs' ops in the SAME
// wave fills those gaps deterministically; barriers per graph halve.
__global__ __launch_bounds__(NT, 4) void sag_fused2(
    const float* __restrict__ x,      // [N, 128]
    const int*   __restrict__ esrc,   // [E]
    const int*   __restrict__ edst,   // [E]
    const float* __restrict__ gcn_w,  // [128]
    const float* __restrict__ gcn_b,  // [1]
    const float* __restrict__ lin_w,  // [256, 128]
    const float* __restrict__ lin_b,  // [128]
    float* __restrict__ out)          // [512, 128]
{
  const int g0   = blockIdx.x * 2;
  const int g1x  = g0 + 1;
  const int tid  = threadIdx.x;
  const int lane = tid & 63;
  const int wave = tid >> 6;          // 0..15
  const int j    = lane & 15;
  const int sub  = lane >> 4;
  const int slot = wave * 4 + sub;    // 0..63

  __shared__ int    sDeg [2][NPER];
  __shared__ int    sRank[2][NPER];
  __shared__ int    sXWi [2][NPER];
  __shared__ __align__(16) int   sFx[2][NPER];
  __shared__ float  sXW  [2][NPER];
  __shared__ float  sDinv[2][NPER];
  __shared__ __align__(16) float sScore[2][NPER];
  __shared__ float2 sGF  [2][NPER];
  __shared__ float  sPoolS[2][16][DD];   // 16KB
  __shared__ float  sPoolM[2][16][DD];   // 16KB
  __shared__ float2 sR2  [2][DD];        // per-graph readout (256 floats each)

  // ---- front-load: edges of both graphs + w + dot-x of both graphs
  const int4* es0 = (const int4*)(esrc + (size_t)g0  * EPER);
  const int4* ed0 = (const int4*)(edst + (size_t)g0  * EPER);
  const int4* es1 = (const int4*)(esrc + (size_t)g1x * EPER);
  const int4* ed1 = (const int4*)(edst + (size_t)g1x * EPER);
  int4 da0 = ed0[tid], da1 = ed1[tid];
  int4 sa0 = es0[tid], sa1 = es1[tid];

  float4 wa = ((const float4*)gcn_w)[j];
  float4 wb = ((const float4*)gcn_w)[16 + j];

  const float4* x0 = (const float4*)(x + (size_t)g0  * NPER * DD);
  const float4* x1 = (const float4*)(x + (size_t)g1x * NPER * DD);
  const int colbase = slot * 32 + j;

  float4 qa0[4], qb0[4], qa1[4], qb1[4];   // dot x-tiles (die at B2)
  #pragma unroll
  for (int r = 0; r < 4; ++r) {
    qa0[r] = x0[r * 2048 + colbase];  qb0[r] = x0[r * 2048 + colbase + 16];
    qa1[r] = x1[r * 2048 + colbase];  qb1[r] = x1[r * 2048 + colbase + 16];
  }

  if (tid < 2 * NPER) { ((int*)sDeg)[tid] = 1; ((int*)sRank)[tid] = 0; }
  BAR();                                              // B1

  // ---- degree, both graphs interleaved (independent LDS-atomic streams)
  atomicAdd(&sDeg[0][da0.x & 255], 1); atomicAdd(&sDeg[1][da1.x & 255], 1);
  atomicAdd(&sDeg[0][da0.y & 255], 1); atomicAdd(&sDeg[1][da1.y & 255], 1);
  atomicAdd(&sDeg[0][da0.z & 255], 1); atomicAdd(&sDeg[1][da1.z & 255], 1);
  atomicAdd(&sDeg[0][da0.w & 255], 1); atomicAdd(&sDeg[1][da1.w & 255], 1);

  // ---- dot, both graphs interleaved (two independent shfl chains)
  #pragma unroll
  for (int r = 0; r < 4; ++r) {
    float a0 = qa0[r].x*wa.x + qa0[r].y*wa.y + qa0[r].z*wa.z + qa0[r].w*wa.w
             + qb0[r].x*wb.x + qb0[r].y*wb.y + qb0[r].z*wb.z + qb0[r].w*wb.w;
    float a1 = qa1[r].x*wa.x + qa1[r].y*wa.y + qa1[r].z*wa.z + qa1[r].w*wa.w
             + qb1[r].x*wb.x + qb1[r].y*wb.y + qb1[r].z*wb.z + qb1[r].w*wb.w;
    a0 += __shfl_xor(a0, 1);  a1 += __shfl_xor(a1, 1);
    a0 += __shfl_xor(a0, 2);  a1 += __shfl_xor(a1, 2);
    a0 += __shfl_xor(a0, 4);  a1 += __shfl_xor(a1, 4);
    a0 += __shfl_xor(a0, 8);  a1 += __shfl_xor(a1, 8);
    if (j == 0) { sXW[0][r * 64 + slot] = a0; sXW[1][r * 64 + slot] = a1; }
  }
  BAR();                                              // B2

  // ---- issue pool-x reloads NOW (L2/L3-hot); in flight across B3..B6
  float4 ua0[4], ub0[4], ua1[4], ub1[4];
  #pragma unroll
  for (int r = 0; r < 4; ++r) {
    ua0[r] = x0[r * 2048 + colbase];  ub0[r] = x0[r * 2048 + colbase + 16];
    ua1[r] = x1[r * 2048 + colbase];  ub1[r] = x1[r * 2048 + colbase + 16];
  }

  if (tid < 2 * NPER) {
    float dv = 1.0f / sqrtf((float)((int*)sDeg)[tid]);
    int   xi = __float2int_rn(((float*)sXW)[tid] * dv * SFX_SCALE);
    ((float*)sDinv)[tid] = dv;
    ((int*)sXWi)[tid]    = xi;
    ((int*)sFx)[tid]     = xi;        // seed: self term's inner factor
  }
  BAR();                                              // B3

  // ---- scatter, both graphs interleaved: gather + native int atomic
  {
    int v0 = sXWi[0][sa0.x & 255], w0 = sXWi[1][sa1.x & 255];
    int v1 = sXWi[0][sa0.y & 255], w1 = sXWi[1][sa1.y & 255];
    int v2 = sXWi[0][sa0.z & 255], w2 = sXWi[1][sa1.z & 255];
    int v3 = sXWi[0][sa0.w & 255], w3 = sXWi[1][sa1.w & 255];
    atomicAdd(&sFx[0][da0.x & 255], v0); atomicAdd(&sFx[1][da1.x & 255], w0);
    atomicAdd(&sFx[0][da0.y & 255], v1); atomicAdd(&sFx[1][da1.y & 255], w1);
    atomicAdd(&sFx[0][da0.z & 255], v2); atomicAdd(&sFx[1][da1.z & 255], w2);
    atomicAdd(&sFx[0][da0.w & 255], v3); atomicAdd(&sFx[1][da1.w & 255], w3);
  }
  BAR();                                              // B4

  if (tid < 2 * NPER)
    ((float*)sScore)[tid] = ((float*)sDinv)[tid] * ((float)((int*)sFx)[tid] * SFX_INV);
  BAR();                                              // B4b

  // ---- stable top-K rank: 2 graphs x 256 nodes x 2 segs = 1024 threads
  {
    int G    = tid >> 9;
    int node = tid & 255;
    int seg  = (tid >> 8) & 1;
    const float4* S4 = (const float4*)sScore[G];
    float s_i = sScore[G][node];
    int base = seg * 32;
    int part = 0;
    #pragma unroll 8
    for (int t = 0; t < 32; ++t) {
      float4 v = S4[base + t];        // same addr across wave -> broadcast
      int jj = (base + t) * 4;
      part += (v.x > s_i) || (v.x == s_i && (jj + 0) < node);
      part += (v.y > s_i) || (v.y == s_i && (jj + 1) < node);
      part += (v.z > s_i) || (v.z == s_i && (jj + 2) < node);
      part += (v.w > s_i) || (v.w == s_i && (jj + 3) < node);
    }
    atomicAdd(&sRank[G][node], part);
  }
  BAR();                                              // B5

  if (tid < 2 * NPER) {
    bool kp = ((int*)sRank)[tid] < KK;
    float gate = tanhf(((float*)sScore)[tid] + gcn_b[0]);
    ((float2*)sGF)[tid] = make_float2(kp ? gate : 0.0f, kp ? 0.0f : INFINITY);
  }
  BAR();                                              // B6

  // ---- pool, graph-sequential (bounds accumulator VGPRs)
  #define RED_S(v) v += __shfl_xor(v,16); v += __shfl_xor(v,32);
  #define RED_M(v) v = fmaxf(v,__shfl_xor(v,16)); v = fmaxf(v,__shfl_xor(v,32));
  #define POOL_ONE(G, UA, UB)                                               \
  {                                                                         \
    float su0=0,su1=0,su2=0,su3=0,su4=0,su5=0,su6=0,su7=0;                  \
    float mx0=-INFINITY,mx1=-INFINITY,mx2=-INFINITY,mx3=-INFINITY;          \
    float mx4=-INFINITY,mx5=-INFINITY,mx6=-INFINITY,mx7=-INFINITY;          \
    _Pragma("unroll")                                                       \
    for (int r = 0; r < 4; ++r) {                                           \
      float2 gf = sGF[G][r * 64 + slot];                                    \
      float gv = gf.x, fb = gf.y, a;                                        \
      a = UA[r].x * gv; su0 += a; mx0 = fmaxf(mx0, a - fb);                 \
      a = UA[r].y * gv; su1 += a; mx1 = fmaxf(mx1, a - fb);                 \
      a = UA[r].z * gv; su2 += a; mx2 = fmaxf(mx2, a - fb);                 \
      a = UA[r].w * gv; su3 += a; mx3 = fmaxf(mx3, a - fb);                 \
      a = UB[r].x * gv; su4 += a; mx4 = fmaxf(mx4, a - fb);                 \
      a = UB[r].y * gv; su5 += a; mx5 = fmaxf(mx5, a - fb);                 \
      a = UB[r].z * gv; su6 += a; mx6 = fmaxf(mx6, a - fb);                 \
      a = UB[r].w * gv; su7 += a; mx7 = fmaxf(mx7, a - fb);                 \
    }                                                                       \
    RED_S(su0) RED_S(su1) RED_S(su2) RED_S(su3)                             \
    RED_S(su4) RED_S(su5) RED_S(su6) RED_S(su7)                             \
    RED_M(mx0) RED_M(mx1) RED_M(mx2) RED_M(mx3)                             \
    RED_M(mx4) RED_M(mx5) RED_M(mx6) RED_M(mx7)                             \
    if (sub == 0) {                                                         \
      ((float4*)&sPoolS[G][wave][4 * j])[0]      = make_float4(su0,su1,su2,su3); \
      ((float4*)&sPoolS[G][wave][64 + 4 * j])[0] = make_float4(su4,su5,su6,su7); \
      ((float4*)&sPoolM[G][wave][4 * j])[0]      = make_float4(mx0,mx1,mx2,mx3); \
      ((float4*)&sPoolM[G][wave][64 + 4 * j])[0] = make_float4(mx4,mx5,mx6,mx7); \
    }                                                                       \
  }
  POOL_ONE(0, ua0, ub0)
  POOL_ONE(1, ua1, ub1)
  BAR();                                              // B7

  // ---- readout reduce: 512 threads cover 2 graphs x (128 mean + 128 max)
  if (tid < 2 * NPER) {
    int G = tid >> 8, idx = tid & 255;
    float* sRf = (float*)sR2[G];
    if (idx < DD) {
      float s = 0.f;
      #pragma unroll
      for (int w = 0; w < 16; ++w) s += sPoolS[G][w][idx];
      sRf[idx] = s * (1.0f / KK);
    } else {
      int d = idx - DD;
      float m = -INFINITY;
      #pragma unroll
      for (int w = 0; w < 16; ++w) m = fmaxf(m, sPoolM[G][w][d]);
      sRf[idx] = m;
    }
  }
  BAR();                                              // B8

  // ---- matvec: waves 0-7 -> g0, waves 8-15 -> g1 (lin_w L2-hot)
  {
    const float2* lw2 = (const float2*)lin_w;
    int G  = wave >> 3;
    int wg = wave & 7;
    float a0 = 0.f, a1 = 0.f;
    #pragma unroll
    for (int t = 0; t < 16; ++t) {
      int k2 = wg * 16 + t;
      float2 rv = sR2[G][k2];
      float2 p0 = lw2[(2 * k2) * 64 + lane];
      float2 p1 = lw2[(2 * k2 + 1) * 64 + lane];
      a0 += rv.x * p0.x + rv.y * p1.x;
      a1 += rv.x * p0.y + rv.y * p1.y;
    }
    float2* sP2 = (float2*)sPoolS;    // reuse: [2][8][64] float2 = 8KB
    sP2[(G * 8 + wg) * 64 + lane] = make_float2(a0, a1);
  }
  BAR();                                              // B9
  if ((wave & 7) == 0) {
    int G = wave >> 3;
    float2* sP2 = (float2*)sPoolS;
    float2 a = sP2[G * 512 + lane];
    #pragma unroll
    for (int w = 1; w < 8; ++w) {
      float2 p = sP2[G * 512 + w * 64 + lane];
      a.x += p.x; a.y += p.y;
    }
    float2 bb = ((const float2*)lin_b)[lane];
    a.x += bb.x; a.y += bb.y;
    ((float2*)out)[(size_t)(g0 + G) * 64 + lane] = a;
  }
}

extern "C" void kernel_launch(void* const* d_in, const int* in_sizes, int n_in,
                              void* d_out, int out_size, void* d_ws, size_t ws_size,
                              hipStream_t stream) {
  const float* x  = (const float*)d_in[0];
  // d_in[1] = graph_indicator (unused: equal-size contiguous graphs)
  const int*   ei = (const int*)d_in[2];
  const float* gw = (const float*)d_in[3];
  const float* gb = (const float*)d_in[4];
  const float* lw = (const float*)d_in[5];
  const float* lb = (const float*)d_in[6];
  float* out = (float*)d_out;
  const int E = in_sizes[2] / 2;      // edge_index is [2, E]
  sag_fused2<<<NG / 2, NT, 0, stream>>>(x, ei, ei + E, gw, gb, lw, lb, out);
}

// Round 10
// 122.715 us; speedup vs baseline: 2.2646x; 1.0665x over previous
//
#include <hip/hip_runtime.h>
#include <math.h>

#define NG   512
#define NPER 256
#define DD   128
#define EPER 4096
#define KK   128
#define NT   512
#define NW   8      // waves per block (convoy width halved vs R6's 16)

#define SFX_SCALE 4194304.0f             // 2^22 (score path, validated R4-R6)
#define SFX_INV   2.384185791015625e-07f // 2^-22
#define PSC_SCALE 1048576.0f             // 2^20 (pool mean path)
#define PSC_INV   9.5367431640625e-07f   // 2^-20

// LDS-only barrier: lgkm drain + s_barrier (no vmcnt drain) — in-flight
// global loads legally span it; compiler inserts counted vmcnt at first use.
#define BAR() asm volatile("s_waitcnt lgkmcnt(0)\ns_barrier" ::: "memory")

// Order-preserving float<->uint encoding for atomic max on LDS.
__device__ __forceinline__ unsigned fenc(float f) {
  unsigned u = __float_as_uint(f);
  return (u & 0x80000000u) ? ~u : (u | 0x80000000u);
}
__device__ __forceinline__ float fdec(unsigned k) {
  return __uint_as_float((k & 0x80000000u) ? (k ^ 0x80000000u) : ~k);
}

// R6 algorithm, restructured per the convoy model (R8/R9 evidence):
//  - 8-wave blocks: each barrier waits 8 wave-bodies, not 16
//  - rank fused with score finalize (one barrier fewer, no sScore buffer)
//  - sFx[2] copies: same-address atomic serialization halved
//  - pool partials via native ds_add/ds_max_u32 (32KB LDS + 1 barrier saved)
__global__ __launch_bounds__(NT, 4) void sag_fused(
    const float* __restrict__ x,      // [N, 128]
    const int*   __restrict__ esrc,   // [E]
    const int*   __restrict__ edst,   // [E]
    const float* __restrict__ gcn_w,  // [128]
    const float* __restrict__ gcn_b,  // [1]
    const float* __restrict__ lin_w,  // [256, 128]
    const float* __restrict__ lin_b,  // [128]
    float* __restrict__ out)          // [512, 128]
{
  const int g    = blockIdx.x;
  const int tid  = threadIdx.x;
  const int lane = tid & 63;
  const int wave = tid >> 6;          // 0..7
  const int j    = lane & 15;
  const int sub  = lane >> 4;
  const int slot = wave * 4 + sub;    // 0..31

  __shared__ int      sDeg[NPER];
  __shared__ int      sRank[NPER];
  __shared__ int      sXWi[NPER];
  __shared__ __align__(16) int sFx[2][NPER];  // 2 copies: contention halving
  __shared__ float    sXW[NPER];
  __shared__ __align__(16) float sDinv[NPER];
  __shared__ float2   sGF[NPER];
  __shared__ int      sRm[DD];        // pool mean: fixed-point sums
  __shared__ unsigned sRx[DD];        // pool max: order-encoded keys
  __shared__ float    sR[2 * DD];     // decoded readout [mean||max]
  __shared__ float2   sP2[NW * 64];   // matvec partials (4KB)

  // ---- front-load all global reads: 4 int4 edges + 2 float4 w + 16 float4 x
  const int4* es4 = (const int4*)(esrc + (size_t)g * EPER);
  const int4* ed4 = (const int4*)(edst + (size_t)g * EPER);
  int4 da0 = ed4[tid], da1 = ed4[NT + tid];
  int4 sa0 = es4[tid], sa1 = es4[NT + tid];

  float4 wa = ((const float4*)gcn_w)[j];
  float4 wb = ((const float4*)gcn_w)[16 + j];

  const float4* xg4 = (const float4*)(x + (size_t)g * NPER * DD);
  const int colbase = slot * 32 + j;  // float4 units
  float4 q0[8], q1[8];
  #pragma unroll
  for (int r = 0; r < 8; ++r) {
    q0[r] = xg4[r * 1024 + colbase];          // node r*32+slot, dims [4j,4j+4)
    q1[r] = xg4[r * 1024 + colbase + 16];     // dims [64+4j, ..)
  }

  // ---- init
  if (tid < NPER)            { sDeg[tid] = 1; sRank[tid] = 0; }
  else if (tid < NPER + DD)  { sRm[tid - NPER] = 0; sRx[tid - NPER] = 0u; }
  BAR();                                              // B1

  // ---- degree (edges only) — native ds_add_u32
  atomicAdd(&sDeg[da0.x & 255], 1); atomicAdd(&sDeg[da0.y & 255], 1);
  atomicAdd(&sDeg[da0.z & 255], 1); atomicAdd(&sDeg[da0.w & 255], 1);
  atomicAdd(&sDeg[da1.x & 255], 1); atomicAdd(&sDeg[da1.y & 255], 1);
  atomicAdd(&sDeg[da1.z & 255], 1); atomicAdd(&sDeg[da1.w & 255], 1);

  // ---- xw dot from registers
  #pragma unroll
  for (int r = 0; r < 8; ++r) {
    float acc = q0[r].x*wa.x + q0[r].y*wa.y + q0[r].z*wa.z + q0[r].w*wa.w
              + q1[r].x*wb.x + q1[r].y*wb.y + q1[r].z*wb.z + q1[r].w*wb.w;
    acc += __shfl_xor(acc, 1);
    acc += __shfl_xor(acc, 2);
    acc += __shfl_xor(acc, 4);
    acc += __shfl_xor(acc, 8);
    if (j == 0) sXW[r * 32 + slot] = acc;
  }
  BAR();                                              // B2

  // ---- seed: xi = round(xw*dinv*2^22); copy0 seeded, copy1 zero
  if (tid < NPER) {
    float dv = 1.0f / sqrtf((float)sDeg[tid]);
    int   xi = __float2int_rn(sXW[tid] * dv * SFX_SCALE);
    sDinv[tid] = dv;
    sXWi[tid]  = xi;
    sFx[0][tid] = xi;                 // self term's inner factor
    sFx[1][tid] = 0;
  }
  BAR();                                              // B3

  // ---- scatter: copy (lane&1) — halves same-address serialization
  {
    int p = lane & 1;
    int v0 = sXWi[sa0.x & 255], v1 = sXWi[sa0.y & 255];
    int v2 = sXWi[sa0.z & 255], v3 = sXWi[sa0.w & 255];
    int v4 = sXWi[sa1.x & 255], v5 = sXWi[sa1.y & 255];
    int v6 = sXWi[sa1.z & 255], v7 = sXWi[sa1.w & 255];
    atomicAdd(&sFx[p][da0.x & 255], v0);
    atomicAdd(&sFx[p][da0.y & 255], v1);
    atomicAdd(&sFx[p][da0.z & 255], v2);
    atomicAdd(&sFx[p][da0.w & 255], v3);
    atomicAdd(&sFx[p][da1.x & 255], v4);
    atomicAdd(&sFx[p][da1.y & 255], v5);
    atomicAdd(&sFx[p][da1.z & 255], v6);
    atomicAdd(&sFx[p][da1.w & 255], v7);
  }
  BAR();                                              // B4

  // ---- rank fused with finalize: score computed on the fly from
  // sFx[0]+sFx[1] and sDinv (identical ops everywhere -> deterministic).
  {
    const int4*   c04 = (const int4*)sFx[0];
    const int4*   c14 = (const int4*)sFx[1];
    const float4* dv4 = (const float4*)sDinv;
    int node = tid & 255;
    int seg  = tid >> 8;              // 0..1
    float s_i = sDinv[node] * ((float)(sFx[0][node] + sFx[1][node]) * SFX_INV);
    int base = seg * 32;
    int part = 0;
    #pragma unroll 8
    for (int t = 0; t < 32; ++t) {
      int4   c0 = c04[base + t];
      int4   c1 = c14[base + t];
      float4 dv = dv4[base + t];
      float vx = dv.x * ((float)(c0.x + c1.x) * SFX_INV);
      float vy = dv.y * ((float)(c0.y + c1.y) * SFX_INV);
      float vz = dv.z * ((float)(c0.z + c1.z) * SFX_INV);
      float vw = dv.w * ((float)(c0.w + c1.w) * SFX_INV);
      int jj = (base + t) * 4;
      part += (vx > s_i) || (vx == s_i && (jj + 0) < node);
      part += (vy > s_i) || (vy == s_i && (jj + 1) < node);
      part += (vz > s_i) || (vz == s_i && (jj + 2) < node);
      part += (vw > s_i) || (vw == s_i && (jj + 3) < node);
    }
    atomicAdd(&sRank[node], part);
  }
  BAR();                                              // B5

  // ---- gate
  if (tid < NPER) {
    bool kp = sRank[tid] < KK;        // ranks are a permutation of 0..255
    float sc = sDinv[tid] * ((float)(sFx[0][tid] + sFx[1][tid]) * SFX_INV);
    float gate = tanhf(sc + gcn_b[0]);
    sGF[tid] = make_float2(kp ? gate : 0.0f, kp ? 0.0f : INFINITY);
  }
  BAR();                                              // B6

  // ---- pool from registers; partial-combine via native LDS atomics
  float su0=0,su1=0,su2=0,su3=0,su4=0,su5=0,su6=0,su7=0;
  float mx0=-INFINITY,mx1=-INFINITY,mx2=-INFINITY,mx3=-INFINITY;
  float mx4=-INFINITY,mx5=-INFINITY,mx6=-INFINITY,mx7=-INFINITY;
  #pragma unroll
  for (int r = 0; r < 8; ++r) {
    float2 gf = sGF[r * 32 + slot];   // broadcast, conflict-free
    float g1 = gf.x, fb = gf.y;
    float a;
    a = q0[r].x * g1; su0 += a; mx0 = fmaxf(mx0, a - fb);
    a = q0[r].y * g1; su1 += a; mx1 = fmaxf(mx1, a - fb);
    a = q0[r].z * g1; su2 += a; mx2 = fmaxf(mx2, a - fb);
    a = q0[r].w * g1; su3 += a; mx3 = fmaxf(mx3, a - fb);
    a = q1[r].x * g1; su4 += a; mx4 = fmaxf(mx4, a - fb);
    a = q1[r].y * g1; su5 += a; mx5 = fmaxf(mx5, a - fb);
    a = q1[r].z * g1; su6 += a; mx6 = fmaxf(mx6, a - fb);
    a = q1[r].w * g1; su7 += a; mx7 = fmaxf(mx7, a - fb);
  }
  #define RED_S(v) v += __shfl_xor(v,16); v += __shfl_xor(v,32);
  #define RED_M(v) v = fmaxf(v,__shfl_xor(v,16)); v = fmaxf(v,__shfl_xor(v,32));
  RED_S(su0) RED_S(su1) RED_S(su2) RED_S(su3)
  RED_S(su4) RED_S(su5) RED_S(su6) RED_S(su7)
  RED_M(mx0) RED_M(mx1) RED_M(mx2) RED_M(mx3)
  RED_M(mx4) RED_M(mx5) RED_M(mx6) RED_M(mx7)
  if (sub == 0) {
    int d0 = 4 * j, d1 = 64 + 4 * j;
    atomicAdd(&sRm[d0 + 0], __float2int_rn(su0 * PSC_SCALE));
    atomicAdd(&sRm[d0 + 1], __float2int_rn(su1 * PSC_SCALE));
    atomicAdd(&sRm[d0 + 2], __float2int_rn(su2 * PSC_SCALE));
    atomicAdd(&sRm[d0 + 3], __float2int_rn(su3 * PSC_SCALE));
    atomicAdd(&sRm[d1 + 0], __float2int_rn(su4 * PSC_SCALE));
    atomicAdd(&sRm[d1 + 1], __float2int_rn(su5 * PSC_SCALE));
    atomicAdd(&sRm[d1 + 2], __float2int_rn(su6 * PSC_SCALE));
    atomicAdd(&sRm[d1 + 3], __float2int_rn(su7 * PSC_SCALE));
    atomicMax(&sRx[d0 + 0], fenc(mx0));
    atomicMax(&sRx[d0 + 1], fenc(mx1));
    atomicMax(&sRx[d0 + 2], fenc(mx2));
    atomicMax(&sRx[d0 + 3], fenc(mx3));
    atomicMax(&sRx[d1 + 0], fenc(mx4));
    atomicMax(&sRx[d1 + 1], fenc(mx5));
    atomicMax(&sRx[d1 + 2], fenc(mx6));
    atomicMax(&sRx[d1 + 3], fenc(mx7));
  }
  BAR();                                              // B7

  // ---- decode readout [mean||max]
  if (tid < DD)          sR[tid] = (float)sRm[tid] * (PSC_INV / (float)KK);
  else if (tid < 2 * DD) sR[tid] = fdec(sRx[tid - DD]);
  BAR();                                              // B8

  // ---- matvec: out = [mean||max] @ lin_w + lin_b
  {
    const float2* lw2 = (const float2*)lin_w;
    const float2* sR2 = (const float2*)sR;
    float a0 = 0.f, a1 = 0.f;
    #pragma unroll
    for (int t = 0; t < 16; ++t) {
      int k2 = wave * 16 + t;
      float2 rv = sR2[k2];
      float2 p0 = lw2[(2 * k2) * 64 + lane];
      float2 p1 = lw2[(2 * k2 + 1) * 64 + lane];
      a0 += rv.x * p0.x + rv.y * p1.x;
      a1 += rv.x * p0.y + rv.y * p1.y;
    }
    sP2[wave * 64 + lane] = make_float2(a0, a1);
  }
  BAR();                                              // B9
  if (wave == 0) {
    float2 a = sP2[lane];
    #pragma unroll
    for (int w = 1; w < NW; ++w) { float2 p = sP2[w * 64 + lane]; a.x += p.x; a.y += p.y; }
    float2 bb = ((const float2*)lin_b)[lane];
    a.x += bb.x; a.y += bb.y;
    ((float2*)out)[(size_t)g * 64 + lane] = a;
  }
}

extern "C" void kernel_launch(void* const* d_in, const int* in_sizes, int n_in,
                              void* d_out, int out_size, void* d_ws, size_t ws_size,
                              hipStream_t stream) {
  const float* x  = (const float*)d_in[0];
  // d_in[1] = graph_indicator (unused: equal-size contiguous graphs)
  const int*   ei = (const int*)d_in[2];
  const float* gw = (const float*)d_in[3];
  const float* gb = (const float*)d_in[4];
  const float* lw = (const float*)d_in[5];
  const float* lb = (const float*)d_in[6];
  float* out = (float*)d_out;
  const int E = in_sizes[2] / 2;      // edge_index is [2, E]
  sag_fused<<<NG, NT, 0, stream>>>(x, ei, ei + E, gw, gb, lw, lb, out);
}

// Round 11
// 119.275 us; speedup vs baseline: 2.3299x; 1.0288x over previous
//
#include <hip/hip_runtime.h>
#include <math.h>

#define NG   512
#define NPER 256
#define DD   128
#define EPER 4096
#define KK   128
#define NT   512
#define NW   8      // waves per block

#define SFX_SCALE 4194304.0f             // 2^22 (validated R4-R6)
#define SFX_INV   2.384185791015625e-07f // 2^-22

// Opaque register redefinition: after this, the compiler cannot prove the
// value equals the global load's result, so it CANNOT rematerialize the
// load for later uses — the x-tile must stay resident in VGPRs to the pool.
// (R0/R1/R10 all show VGPR_Count < |x-tile| -> every prior variant secretly
// re-loaded x from global AFTER the gate phase, serialized: the hidden
// ~7-10us that made the pool path ~17us in the R8 probe decomposition.)
#define KEEP4(v) asm volatile("" : "+v"(v.x), "+v"(v.y), "+v"(v.z), "+v"(v.w))

// R4/R6 best structure at NT=512, launch_bounds(512,4): VGPR cap 128 while
// keeping 16 waves/CU = 2 blocks/CU (wave-count halving proven neutral,
// R0==R1). x loaded from global EXACTLY once.
__global__ __launch_bounds__(NT, 4) void sag_fused(
    const float* __restrict__ x,      // [N, 128]
    const int*   __restrict__ esrc,   // [E]
    const int*   __restrict__ edst,   // [E]
    const float* __restrict__ gcn_w,  // [128]
    const float* __restrict__ gcn_b,  // [1]
    const float* __restrict__ lin_w,  // [256, 128]
    const float* __restrict__ lin_b,  // [128]
    float* __restrict__ out)          // [512, 128]
{
  const int g    = blockIdx.x;
  const int tid  = threadIdx.x;
  const int lane = tid & 63;
  const int wave = tid >> 6;          // 0..7
  const int j    = lane & 15;
  const int sub  = lane >> 4;
  const int slot = wave * 4 + sub;    // 0..31

  __shared__ int    sDeg[NPER];
  __shared__ int    sRank[NPER];
  __shared__ int    sXWi[NPER];
  __shared__ __align__(16) int   sFx[NPER];
  __shared__ float  sXW[NPER];
  __shared__ float  sDinv[NPER];
  __shared__ __align__(16) float sScore[NPER];
  __shared__ float2 sGF[NPER];
  __shared__ float  sPoolS[NW][DD];
  __shared__ float  sPoolM[NW][DD];
  __shared__ float2 sR2[DD];
  float* sR = (float*)sR2;

  // ---- front-load ALL global reads: 4 int4 edges + 2 float4 w + 16 float4 x
  const int4* es4 = (const int4*)(esrc + (size_t)g * EPER);
  const int4* ed4 = (const int4*)(edst + (size_t)g * EPER);
  int4 sa = es4[tid], sb = es4[NT + tid];
  int4 da = ed4[tid], db = ed4[NT + tid];

  float4 wa = ((const float4*)gcn_w)[j];
  float4 wb = ((const float4*)gcn_w)[16 + j];

  const float4* xg4 = (const float4*)(x + (size_t)g * NPER * DD);
  const int colbase = slot * 32 + j;  // float4 units
  float4 q0[8], q1[8];
  #pragma unroll
  for (int r = 0; r < 8; ++r) {
    q0[r] = xg4[r * 1024 + colbase];          // node r*32+slot, dims [4j,4j+4)
    q1[r] = xg4[r * 1024 + colbase + 16];     // dims [64+4j, ..)
  }

  if (tid < NPER) { sDeg[tid] = 1; sRank[tid] = 0; }
  __syncthreads();                                      // B1

  // ---- degree (edges only) — native ds_add_u32
  atomicAdd(&sDeg[da.x & 255], 1);
  atomicAdd(&sDeg[da.y & 255], 1);
  atomicAdd(&sDeg[da.z & 255], 1);
  atomicAdd(&sDeg[da.w & 255], 1);
  atomicAdd(&sDeg[db.x & 255], 1);
  atomicAdd(&sDeg[db.y & 255], 1);
  atomicAdd(&sDeg[db.z & 255], 1);
  atomicAdd(&sDeg[db.w & 255], 1);

  // ---- xw dot from registers
  #pragma unroll
  for (int r = 0; r < 8; ++r) {
    float acc = q0[r].x*wa.x + q0[r].y*wa.y + q0[r].z*wa.z + q0[r].w*wa.w
              + q1[r].x*wb.x + q1[r].y*wb.y + q1[r].z*wb.z + q1[r].w*wb.w;
    acc += __shfl_xor(acc, 1);
    acc += __shfl_xor(acc, 2);
    acc += __shfl_xor(acc, 4);
    acc += __shfl_xor(acc, 8);
    if (j == 0) sXW[r * 32 + slot] = acc;
  }
  // ---- pin the x-tile in VGPRs (no remat / no second global read)
  #pragma unroll
  for (int r = 0; r < 8; ++r) { KEEP4(q0[r]); KEEP4(q1[r]); }
  __syncthreads();                                      // B2

  if (tid < NPER) {
    float dv = 1.0f / sqrtf((float)sDeg[tid]);
    int   xi = __float2int_rn(sXW[tid] * dv * SFX_SCALE);
    sDinv[tid] = dv;
    sXWi[tid]  = xi;                  // per-edge scatter value (read-only next)
    sFx[tid]   = xi;                  // seed: self term's inner factor
  }
  __syncthreads();                                      // B3

  // ---- scatter: sFx[dst] += sXWi[src] — 1 gather + 1 native int atomic
  {
    int v0 = sXWi[sa.x & 255], v1 = sXWi[sa.y & 255];
    int v2 = sXWi[sa.z & 255], v3 = sXWi[sa.w & 255];
    int v4 = sXWi[sb.x & 255], v5 = sXWi[sb.y & 255];
    int v6 = sXWi[sb.z & 255], v7 = sXWi[sb.w & 255];
    atomicAdd(&sFx[da.x & 255], v0);
    atomicAdd(&sFx[da.y & 255], v1);
    atomicAdd(&sFx[da.z & 255], v2);
    atomicAdd(&sFx[da.w & 255], v3);
    atomicAdd(&sFx[db.x & 255], v4);
    atomicAdd(&sFx[db.y & 255], v5);
    atomicAdd(&sFx[db.z & 255], v6);
    atomicAdd(&sFx[db.w & 255], v7);
  }
  __syncthreads();                                      // B4

  // ---- finalize: score[d] = dinv[d] * sum * 2^-22
  if (tid < NPER) sScore[tid] = sDinv[tid] * ((float)sFx[tid] * SFX_INV);
  __syncthreads();                                      // B4b

  // ---- stable top-K rank (2 threads/node, b128 broadcast reads)
  {
    const float4* sScore4 = (const float4*)sScore;
    int node = tid & 255;
    int seg  = tid >> 8;              // 0..1
    float s_i = sScore[node];
    int base = seg * 32;
    int part = 0;
    #pragma unroll 8
    for (int t = 0; t < 32; ++t) {
      float4 v = sScore4[base + t];
      int jj = (base + t) * 4;
      part += (v.x > s_i) || (v.x == s_i && (jj + 0) < node);
      part += (v.y > s_i) || (v.y == s_i && (jj + 1) < node);
      part += (v.z > s_i) || (v.z == s_i && (jj + 2) < node);
      part += (v.w > s_i) || (v.w == s_i && (jj + 3) < node);
    }
    atomicAdd(&sRank[node], part);
  }
  __syncthreads();                                      // B5

  if (tid < NPER) {
    bool kp = sRank[tid] < KK;        // ranks are a permutation of 0..255
    float gate = tanhf(sScore[tid] + gcn_b[0]);
    sGF[tid] = make_float2(kp ? gate : 0.0f, kp ? 0.0f : INFINITY);
  }
  __syncthreads();                                      // B6

  // ---- pool straight from the pinned registers (NO second x read)
  float su0=0,su1=0,su2=0,su3=0,su4=0,su5=0,su6=0,su7=0;
  float mx0=-INFINITY,mx1=-INFINITY,mx2=-INFINITY,mx3=-INFINITY;
  float mx4=-INFINITY,mx5=-INFINITY,mx6=-INFINITY,mx7=-INFINITY;
  #pragma unroll
  for (int r = 0; r < 8; ++r) {
    float2 gf = sGF[r * 32 + slot];   // broadcast, conflict-free
    float g1 = gf.x, fb = gf.y;
    float a;
    a = q0[r].x * g1; su0 += a; mx0 = fmaxf(mx0, a - fb);
    a = q0[r].y * g1; su1 += a; mx1 = fmaxf(mx1, a - fb);
    a = q0[r].z * g1; su2 += a; mx2 = fmaxf(mx2, a - fb);
    a = q0[r].w * g1; su3 += a; mx3 = fmaxf(mx3, a - fb);
    a = q1[r].x * g1; su4 += a; mx4 = fmaxf(mx4, a - fb);
    a = q1[r].y * g1; su5 += a; mx5 = fmaxf(mx5, a - fb);
    a = q1[r].z * g1; su6 += a; mx6 = fmaxf(mx6, a - fb);
    a = q1[r].w * g1; su7 += a; mx7 = fmaxf(mx7, a - fb);
  }
  #define RED_S(v) v += __shfl_xor(v,16); v += __shfl_xor(v,32);
  #define RED_M(v) v = fmaxf(v,__shfl_xor(v,16)); v = fmaxf(v,__shfl_xor(v,32));
  RED_S(su0) RED_S(su1) RED_S(su2) RED_S(su3)
  RED_S(su4) RED_S(su5) RED_S(su6) RED_S(su7)
  RED_M(mx0) RED_M(mx1) RED_M(mx2) RED_M(mx3)
  RED_M(mx4) RED_M(mx5) RED_M(mx6) RED_M(mx7)
  if (sub == 0) {
    ((float4*)&sPoolS[wave][4 * j])[0]      = make_float4(su0, su1, su2, su3);
    ((float4*)&sPoolS[wave][64 + 4 * j])[0] = make_float4(su4, su5, su6, su7);
    ((float4*)&sPoolM[wave][4 * j])[0]      = make_float4(mx0, mx1, mx2, mx3);
    ((float4*)&sPoolM[wave][64 + 4 * j])[0] = make_float4(mx4, mx5, mx6, mx7);
  }
  __syncthreads();                                      // B7

  if (tid < DD) {                     // mean dims
    float s = 0.f;
    #pragma unroll
    for (int w = 0; w < NW; ++w) s += sPoolS[w][tid];
    sR[tid] = s * (1.0f / KK);
  } else if (tid < 2 * DD) {          // max dims
    int d = tid - DD;
    float m = -INFINITY;
    #pragma unroll
    for (int w = 0; w < NW; ++w) m = fmaxf(m, sPoolM[w][d]);
    sR[tid] = m;
  }
  __syncthreads();                                      // B8

  // ---- matvec: out = [mean||max] @ lin_w + lin_b (lin_w L2-hot)
  const float2* lw2 = (const float2*)lin_w;
  float a0 = 0.f, a1 = 0.f;
  #pragma unroll
  for (int t = 0; t < 16; ++t) {
    int k2 = wave * 16 + t;
    float2 rv = sR2[k2];
    float2 p0 = lw2[(2 * k2) * 64 + lane];
    float2 p1 = lw2[(2 * k2 + 1) * 64 + lane];
    a0 += rv.x * p0.x + rv.y * p1.x;
    a1 += rv.x * p0.y + rv.y * p1.y;
  }
  float2* sP2 = (float2*)sPoolS;      // reuse as matvec partials
  sP2[wave * 64 + lane] = make_float2(a0, a1);
  __syncthreads();                                      // B9
  if (wave == 0) {
    float2 a = sP2[lane];
    #pragma unroll
    for (int w = 1; w < NW; ++w) { float2 p = sP2[w * 64 + lane]; a.x += p.x; a.y += p.y; }
    float2 bb = ((const float2*)lin_b)[lane];
    a.x += bb.x; a.y += bb.y;
    ((float2*)out)[(size_t)g * 64 + lane] = a;
  }
}

extern "C" void kernel_launch(void* const* d_in, const int* in_sizes, int n_in,
                              void* d_out, int out_size, void* d_ws, size_t ws_size,
                              hipStream_t stream) {
  const float* x  = (const float*)d_in[0];
  // d_in[1] = graph_indicator (unused: equal-size contiguous graphs)
  const int*   ei = (const int*)d_in[2];
  const float* gw = (const float*)d_in[3];
  const float* gb = (const float*)d_in[4];
  const float* lw = (const float*)d_in[5];
  const float* lb = (const float*)d_in[6];
  float* out = (float*)d_out;
  const int E = in_sizes[2] / 2;      // edge_index is [2, E]
  sag_fused<<<NG, NT, 0, stream>>>(x, ei, ei + E, gw, gb, lw, lb, out);
}